// Round 13
// baseline (311.583 us; speedup 1.0000x reference)
//
#include <hip/hip_runtime.h>

#define R_ 8
#define N_ 4096
#define D_ 128
#define BM 64
#define KSPLIT 2

typedef __attribute__((ext_vector_type(8))) short bf16x8;
typedef __attribute__((ext_vector_type(4))) float f32x4;

__device__ __forceinline__ unsigned short f2bf(float f) {
  unsigned int u = __builtin_bit_cast(unsigned int, f);
  u += 0x7FFFu + ((u >> 16) & 1u);   // RNE
  return (unsigned short)(u >> 16);
}
__device__ __forceinline__ unsigned int pk2(float lo, float hi) {
  return (unsigned int)f2bf(lo) | ((unsigned int)f2bf(hi) << 16);
}
// quantize 4 floats in [0,1) to u8 (value*256, RN, clamp 255), packed LE
__device__ __forceinline__ unsigned int quant4(f32x4 a) {
  unsigned int q0 = (unsigned int)fminf(fmaf(a.x, 256.f, 0.5f), 255.5f);
  unsigned int q1 = (unsigned int)fminf(fmaf(a.y, 256.f, 0.5f), 255.5f);
  unsigned int q2 = (unsigned int)fminf(fmaf(a.z, 256.f, 0.5f), 255.5f);
  unsigned int q3 = (unsigned int)fminf(fmaf(a.w, 256.f, 0.5f), 255.5f);
  return q0 | (q1 << 8) | (q2 << 16) | (q3 << 24);
}

// async global->LDS, 16 B per lane; LDS dest is wave-uniform base + lane*16
__device__ __forceinline__ void gld16(const void* g, void* l) {
  using GP = const __attribute__((address_space(1))) unsigned int*;
  using LP = __attribute__((address_space(3))) unsigned int*;
  __builtin_amdgcn_global_load_lds((GP)g, (LP)l, 16, 0, 0);
}

// embT[d][n] = bf16(emb[n][d])  (unscaled: layer-1 B operand)
__global__ void k_init_embT(const float* __restrict__ emb, unsigned short* __restrict__ embT) {
  int i = blockIdx.x * 256 + threadIdx.x;     // i indexes embT flat [d][n]
  int d = i >> 12, n = i & 4095;
  embT[i] = f2bf(emb[(size_t)n * D_ + d]);
}

__global__ void k_init_rel(const float* __restrict__ rel, unsigned short* __restrict__ relb) {
  int i = blockIdx.x * 256 + threadIdx.x;     // over R*D*D
  relb[i] = f2bf(rel[i]);
}

// ---- Layer-1 GEMM: fp32 adj, BK=128 (512 B/row visit), A-only LDS (32 KB -> 4 blocks/CU),
//      B direct from L2-resident embT with one-kk-ahead register prefetch, fused u8 quant-out.
// adj8 layout per (r,ntile): K-group G = z*64 + t*4 + kk; byte (G*2+wr)*1024 + lane*16
// holds uint4 [m0:a0,a1][m1:a0,a1] quantized — same keying round-10's gemm2 reads.
__global__ __launch_bounds__(256, 4) void gcn_gemm1(
    const float* __restrict__ adj,            // [R][N][N] fp32
    const unsigned short* __restrict__ embT,  // [D][N] bf16 (B^T layout)
    unsigned char* __restrict__ adj8,         // [R*64 tiles][256 KB] u8 tiled
    unsigned short* __restrict__ agg_p)       // [KSPLIT][R][N][D] bf16
{
  __shared__ float As[BM * 128];              // 32 KB: slot s stored at s^(row&15)

  const int tid  = threadIdx.x;
  const int lane = tid & 63;
  const int w    = tid >> 6;
  const int wr = w >> 1, wc = w & 1;          // 2x2 waves: 32 rows x 64 cols each
  const int fr  = lane & 15;
  const int g   = lane >> 4;                  // 0..3
  const int cr4 = g * 4;

  const int ntile = blockIdx.x;
  const int r     = blockIdx.y;
  const int z     = blockIdx.z;
  const int row0  = ntile * BM;
  const int k0    = z * (N_ / KSPLIT);
  const size_t tbase = (size_t)(r * 64 + ntile) * 262144;   // 256 KB per tile

  const float* gAr = adj + ((size_t)r * N_ + row0) * N_ + k0;

  // B fragment base pointers (per lane, includes this lane's k8 = g*8)
  const unsigned short* bptr[4];
#pragma unroll
  for (int n = 0; n < 4; ++n)
    bptr[n] = embT + (size_t)(wc * 64 + n * 16 + fr) * N_ + g * 8;

  bf16x8 bcur[4], bnxt[4];
#pragma unroll
  for (int n = 0; n < 4; ++n) bcur[n] = *(const bf16x8*)(bptr[n] + k0);

  f32x4 acc[2][4];
#pragma unroll
  for (int m = 0; m < 2; ++m)
#pragma unroll
    for (int n = 0; n < 4; ++n)
      acc[m][n] = (f32x4){0.f, 0.f, 0.f, 0.f};

  for (int t = 0; t < 16; ++t) {              // NSTEP = 2048/128
    const int ko = t * 128;
    // A: 8 instrs/wave, each 1 KB = 2 rows x 512 B (32 slots); source pre-swizzled
#pragma unroll
    for (int i = 0; i < 8; ++i) {
      const int rowbase = w * 16 + i * 2;
      const int ra   = rowbase + (lane >> 5);
      const int slot = (lane & 31) ^ (ra & 15);
      gld16(gAr + (size_t)ra * N_ + ko + slot * 4, As + rowbase * 128);
    }
    __syncthreads();                          // drain DMA -> A tile resident

#pragma unroll
    for (int kk = 0; kk < 4; ++kk) {
      // prefetch B for next kk (wrap to next t's first group; t=15 wrap harmless)
      int nko = ko + (kk + 1) * 32;
      if (kk == 3) nko = (t + 1 < 16) ? (t + 1) * 128 : 0;
#pragma unroll
      for (int n = 0; n < 4; ++n) bnxt[n] = *(const bf16x8*)(bptr[n] + k0 + nko);

      bf16x8 af[2];
      uint4 qv;
#pragma unroll
      for (int m = 0; m < 2; ++m) {
        const int row = wr * 32 + m * 16 + fr;
        const int s0  = kk * 8 + g * 2;       // 16-B slot of this lane's k8 (f32)
        f32x4 a0 = *(const f32x4*)&As[row * 128 + (((s0    ) ^ (row & 15)) * 4)];
        f32x4 a1 = *(const f32x4*)&As[row * 128 + (((s0 + 1) ^ (row & 15)) * 4)];
        unsigned int* ap = (unsigned int*)&af[m];
        ap[0] = pk2(a0.x, a0.y); ap[1] = pk2(a0.z, a0.w);
        ap[2] = pk2(a1.x, a1.y); ap[3] = pk2(a1.z, a1.w);
        if (wc == 0) {
          if (m == 0) { qv.x = quant4(a0); qv.y = quant4(a1); }
          else        { qv.z = quant4(a0); qv.w = quant4(a1); }
        }
      }
      if (wc == 0) {
        const int G = z * 64 + t * 4 + kk;    // absolute 32-col K-group
        *(uint4*)(adj8 + tbase + (size_t)(G * 2 + wr) * 1024 + (size_t)lane * 16) = qv;
      }
#pragma unroll
      for (int m = 0; m < 2; ++m)
#pragma unroll
        for (int n = 0; n < 4; ++n)
          acc[m][n] = __builtin_amdgcn_mfma_f32_16x16x32_bf16(af[m], bcur[n], acc[m][n], 0, 0, 0);
#pragma unroll
      for (int n = 0; n < 4; ++n) bcur[n] = bnxt[n];
    }
    __syncthreads();                          // protect LDS overwrite next step
  }

  unsigned short* gO = agg_p + (((size_t)z * R_ + r) * N_ + row0) * D_;
#pragma unroll
  for (int m = 0; m < 2; ++m)
#pragma unroll
    for (int n = 0; n < 4; ++n)
#pragma unroll
      for (int j = 0; j < 4; ++j) {
        int rl = wr * 32 + m * 16 + cr4 + j;
        int cl = wc * 64 + n * 16 + fr;
        gO[(size_t)rl * D_ + cl] = f2bf(acc[m][n][j]);
      }
}

// ---- Layer-2 GEMM: u8 tiled adj (4x fewer bytes), dense sequential reads (R10 verbatim) ----
__global__ __launch_bounds__(256, 4) void gcn_gemm2(
    const unsigned char* __restrict__ adj8,   // tiled u8 (from gemm1)
    const unsigned short* __restrict__ embT,  // [D][N] bf16, scaled 1/256
    unsigned short* __restrict__ agg_p)       // [KSPLIT][R][N][D] bf16
{
  __shared__ unsigned char  A8[64 * 64];      // 4 KB: linear copy of one step-tile
  __shared__ unsigned short Bs[D_ * 64];      // 16 KB: slot s stored at s^(d&7)

  const int tid  = threadIdx.x;
  const int lane = tid & 63;
  const int w    = tid >> 6;
  const int wr = w >> 1, wc = w & 1;
  const int fr  = lane & 15;
  const int g   = lane >> 4;
  const int cr4 = g * 4;

  const int ntile = blockIdx.x;
  const int r     = blockIdx.y;
  const int z     = blockIdx.z;
  const int row0  = ntile * BM;
  const int k0    = z * (N_ / KSPLIT);
  const size_t tbase = (size_t)(r * 64 + ntile) * 262144;

  f32x4 acc[2][4];
#pragma unroll
  for (int m = 0; m < 2; ++m)
#pragma unroll
    for (int n = 0; n < 4; ++n)
      acc[m][n] = (f32x4){0.f, 0.f, 0.f, 0.f};

  for (int t = 0; t < 32; ++t) {              // BK=64 steps
    const int S = z * 32 + t;
    // A: 1 instr/wave; wave w stages chunk w (1 KB), pure sequential memcpy
    gld16(adj8 + tbase + (size_t)S * 4096 + (size_t)w * 1024 + (size_t)lane * 16,
          A8 + w * 1024);
    // B: 4 instrs/wave, each 1 KB = 8 rows x 128 B (8 slots); source pre-swizzled
#pragma unroll
    for (int i = 0; i < 4; ++i) {
      const int rowbase = (w * 4 + i) * 8;
      const int rb   = rowbase + (lane >> 3);
      const int slot = (lane & 7) ^ (rb & 7);
      gld16(embT + (size_t)rb * N_ + k0 + t * 64 + slot * 8, Bs + rowbase * 64);
    }
    __syncthreads();

#pragma unroll
    for (int kk = 0; kk < 2; ++kk) {
      bf16x8 af[2], bfr[4];
      uint4 q = *(const uint4*)&A8[((kk * 2 + wr) * 64 + lane) * 16];
      unsigned int* a0 = (unsigned int*)&af[0];
      unsigned int* a1 = (unsigned int*)&af[1];
      a0[0] = pk2((float)(q.x & 255), (float)((q.x >> 8) & 255));
      a0[1] = pk2((float)((q.x >> 16) & 255), (float)(q.x >> 24));
      a0[2] = pk2((float)(q.y & 255), (float)((q.y >> 8) & 255));
      a0[3] = pk2((float)((q.y >> 16) & 255), (float)(q.y >> 24));
      a1[0] = pk2((float)(q.z & 255), (float)((q.z >> 8) & 255));
      a1[1] = pk2((float)((q.z >> 16) & 255), (float)(q.z >> 24));
      a1[2] = pk2((float)(q.w & 255), (float)((q.w >> 8) & 255));
      a1[3] = pk2((float)((q.w >> 16) & 255), (float)(q.w >> 24));
#pragma unroll
      for (int n = 0; n < 4; ++n) {
        const int d = wc * 64 + n * 16 + fr;
        bfr[n] = *(const bf16x8*)&Bs[d * 64 + (((kk * 4 + g) ^ (d & 7)) * 8)];
      }
#pragma unroll
      for (int m = 0; m < 2; ++m)
#pragma unroll
        for (int n = 0; n < 4; ++n)
          acc[m][n] = __builtin_amdgcn_mfma_f32_16x16x32_bf16(af[m], bfr[n], acc[m][n], 0, 0, 0);
    }
    __syncthreads();
  }

  unsigned short* gO = agg_p + (((size_t)z * R_ + r) * N_ + row0) * D_;
#pragma unroll
  for (int m = 0; m < 2; ++m)
#pragma unroll
    for (int n = 0; n < 4; ++n)
#pragma unroll
      for (int j = 0; j < 4; ++j) {
        int rl = wr * 32 + m * 16 + cr4 + j;
        int cl = wc * 64 + n * 16 + fr;
        gO[(size_t)rl * D_ + cl] = f2bf(acc[m][n][j]);
      }
}

// Pass 2: tmp = agg_p @ rel^T summed over z,r; out = relu(mean_r); embT (scaled) for layer 2
__global__ __launch_bounds__(256) void gcn_pass2(
    const unsigned short* __restrict__ agg_p,  // [KSPLIT][R][N][D] bf16
    const unsigned short* __restrict__ relb,   // [R][D][D] bf16
    float* __restrict__ out,                   // [N][D] f32
    unsigned short* __restrict__ embT,         // [D][N] bf16
    int write_out, int write_embT)
{
  const int tid  = threadIdx.x;
  const int lane = tid & 63;
  const int w    = tid >> 6;
  const int n0   = blockIdx.x * 16;
  const int col0 = w * 32;
  const int fr   = lane & 15;
  const int e8   = (lane >> 4) * 8;
  const int cr4  = (lane >> 4) * 4;

  f32x4 tacc[2];
  tacc[0] = (f32x4){0.f, 0.f, 0.f, 0.f};
  tacc[1] = (f32x4){0.f, 0.f, 0.f, 0.f};

  for (int r = 0; r < R_; ++r) {
    bf16x8 a[2][4], b[2][4];
#pragma unroll
    for (int zz = 0; zz < 2; ++zz)
#pragma unroll
      for (int kk = 0; kk < 4; ++kk)
        a[zz][kk] = *(const bf16x8*)&agg_p[(((size_t)zz * R_ + r) * N_ + n0 + fr) * D_ + kk * 32 + e8];
#pragma unroll
    for (int n = 0; n < 2; ++n)
#pragma unroll
      for (int kk = 0; kk < 4; ++kk)
        b[n][kk] = *(const bf16x8*)&relb[(size_t)r * D_ * D_ + (col0 + n * 16 + fr) * D_ + kk * 32 + e8];
#pragma unroll
    for (int n = 0; n < 2; ++n)
#pragma unroll
      for (int kk = 0; kk < 4; ++kk)
#pragma unroll
        for (int zz = 0; zz < 2; ++zz)
          tacc[n] = __builtin_amdgcn_mfma_f32_16x16x32_bf16(a[zz][kk], b[n][kk], tacc[n], 0, 0, 0);
  }

#pragma unroll
  for (int n = 0; n < 2; ++n)
#pragma unroll
    for (int j = 0; j < 4; ++j) {
      int row = n0 + cr4 + j;
      int col = col0 + n * 16 + fr;
      float v = tacc[n][j] * 0.125f;
      v = v > 0.f ? v : 0.f;
      if (write_out)  out[(size_t)row * D_ + col] = v;
      if (write_embT) embT[(size_t)col * N_ + row] = f2bf(v * 0.00390625f);  // fold 1/256 for u8 layer-2
    }
}

extern "C" void kernel_launch(void* const* d_in, const int* in_sizes, int n_in,
                              void* d_out, int out_size, void* d_ws, size_t ws_size,
                              hipStream_t stream) {
  const float* adj = (const float*)d_in[0];   // [R][N][N]
  const float* emb = (const float*)d_in[1];   // [N][D]
  const float* rel = (const float*)d_in[2];   // [R][D][D]
  float* out = (float*)d_out;                 // [N][D] f32

  unsigned short* embT  = (unsigned short*)d_ws;                 // 1 MB
  unsigned short* relb  = embT + (size_t)N_ * D_;                // 256 KB
  unsigned short* agg_p = relb + (size_t)R_ * D_ * D_;           // 16 MB
  unsigned char*  adj8  = (unsigned char*)(agg_p + (size_t)2 * R_ * N_ * D_);  // 128 MB

  k_init_embT<<<(N_ * D_) / 256, 256, 0, stream>>>(emb, embT);
  k_init_rel<<<(R_ * D_ * D_) / 256, 256, 0, stream>>>(rel, relb);

  dim3 grid(N_ / BM, R_, KSPLIT);
  gcn_gemm1<<<grid, 256, 0, stream>>>(adj, embT, adj8, agg_p);
  gcn_pass2<<<N_ / 16, 256, 0, stream>>>(agg_p, relb, out, embT, /*write_out=*/0, /*write_embT=*/1);
  gcn_gemm2<<<grid, 256, 0, stream>>>(adj8, embT, agg_p);
  gcn_pass2<<<N_ / 16, 256, 0, stream>>>(agg_p, relb, out, embT, /*write_out=*/1, /*write_embT=*/0);
}

// Round 14
// 243.882 us; speedup vs baseline: 1.2776x; 1.2776x over previous
//
#include <hip/hip_runtime.h>

#define R_ 8
#define N_ 4096
#define D_ 128
#define BM 64
#define KSPLIT 2

typedef __attribute__((ext_vector_type(8))) short bf16x8;
typedef __attribute__((ext_vector_type(4))) float f32x4;

__device__ __forceinline__ unsigned short f2bf(float f) {
  unsigned int u = __builtin_bit_cast(unsigned int, f);
  u += 0x7FFFu + ((u >> 16) & 1u);   // RNE
  return (unsigned short)(u >> 16);
}
__device__ __forceinline__ unsigned int pk2(float lo, float hi) {
  return (unsigned int)f2bf(lo) | ((unsigned int)f2bf(hi) << 16);
}
// quantize 4 floats in [0,1) to u8 (value*256, RN, clamp 255), packed LE
__device__ __forceinline__ unsigned int quant4(f32x4 a) {
  unsigned int q0 = (unsigned int)fminf(fmaf(a.x, 256.f, 0.5f), 255.5f);
  unsigned int q1 = (unsigned int)fminf(fmaf(a.y, 256.f, 0.5f), 255.5f);
  unsigned int q2 = (unsigned int)fminf(fmaf(a.z, 256.f, 0.5f), 255.5f);
  unsigned int q3 = (unsigned int)fminf(fmaf(a.w, 256.f, 0.5f), 255.5f);
  return q0 | (q1 << 8) | (q2 << 16) | (q3 << 24);
}

// async global->LDS, 16 B per lane; LDS dest is wave-uniform base + lane*16
__device__ __forceinline__ void gld16(const void* g, void* l) {
  using GP = const __attribute__((address_space(1))) unsigned int*;
  using LP = __attribute__((address_space(3))) unsigned int*;
  __builtin_amdgcn_global_load_lds((GP)g, (LP)l, 16, 0, 0);
}

// embT[d][n] = bf16(emb[n][d])  (unscaled: layer-1 B operand)
__global__ void k_init_embT(const float* __restrict__ emb, unsigned short* __restrict__ embT) {
  int i = blockIdx.x * 256 + threadIdx.x;     // i indexes embT flat [d][n]
  int d = i >> 12, n = i & 4095;
  embT[i] = f2bf(emb[(size_t)n * D_ + d]);
}

__global__ void k_init_rel(const float* __restrict__ rel, unsigned short* __restrict__ relb) {
  int i = blockIdx.x * 256 + threadIdx.x;     // over R*D*D
  relb[i] = f2bf(rel[i]);
}

// ---- Layer-1 GEMM (R12 verbatim): fp32 adj, BK=128, fused u8 quant-out ----
__global__ __launch_bounds__(256, 2) void gcn_gemm1(
    const float* __restrict__ adj,            // [R][N][N] fp32
    const unsigned short* __restrict__ embT,  // [D][N] bf16 (B^T layout)
    unsigned char* __restrict__ adj8,         // [R*64 tiles][256 KB] u8 tiled
    unsigned short* __restrict__ agg_p)       // [KSPLIT][R][N][D] bf16
{
  __shared__ float          As[BM * 128];     // 32 KB: slot s stored at s^(row&15)
  __shared__ unsigned short Bs[D_ * 128];     // 32 KB: slot s stored at s^(d&15)

  const int tid  = threadIdx.x;
  const int lane = tid & 63;
  const int w    = tid >> 6;
  const int wr = w >> 1, wc = w & 1;          // 2x2 waves: 32 rows x 64 cols each
  const int fr  = lane & 15;
  const int g   = lane >> 4;                  // 0..3
  const int cr4 = g * 4;

  const int ntile = blockIdx.x;
  const int r     = blockIdx.y;
  const int z     = blockIdx.z;
  const int row0  = ntile * BM;
  const int k0    = z * (N_ / KSPLIT);
  const size_t tbase = (size_t)(r * 64 + ntile) * 262144;   // 256 KB per tile

  const float* gAr = adj + ((size_t)r * N_ + row0) * N_ + k0;

  f32x4 acc[2][4];
#pragma unroll
  for (int m = 0; m < 2; ++m)
#pragma unroll
    for (int n = 0; n < 4; ++n)
      acc[m][n] = (f32x4){0.f, 0.f, 0.f, 0.f};

  for (int t = 0; t < 16; ++t) {              // NSTEP = 2048/128
    const int ko = t * 128;
    // A: 8 instrs/wave, each 1 KB = 2 rows x 512 B (32 slots); source pre-swizzled
#pragma unroll
    for (int i = 0; i < 8; ++i) {
      const int rowbase = w * 16 + i * 2;
      const int ra   = rowbase + (lane >> 5);
      const int slot = (lane & 31) ^ (ra & 15);
      gld16(gAr + (size_t)ra * N_ + ko + slot * 4, As + rowbase * 128);
    }
    // B: 8 instrs/wave, each 1 KB = 4 rows x 256 B (16 slots); source pre-swizzled
#pragma unroll
    for (int i = 0; i < 8; ++i) {
      const int rowbase = (w * 8 + i) * 4;
      const int d    = rowbase + (lane >> 4);
      const int slot = (lane & 15) ^ (d & 15);
      gld16(embT + (size_t)d * N_ + k0 + ko + slot * 8, Bs + rowbase * 128);
    }
    __syncthreads();                          // drain DMA -> tile resident

#pragma unroll
    for (int kk = 0; kk < 4; ++kk) {
      bf16x8 af[2], bfr[4];
      uint4 qv;
#pragma unroll
      for (int m = 0; m < 2; ++m) {
        const int row = wr * 32 + m * 16 + fr;
        const int s0  = kk * 8 + g * 2;       // 16-B slot of this lane's k8 (f32)
        f32x4 a0 = *(const f32x4*)&As[row * 128 + (((s0    ) ^ (row & 15)) * 4)];
        f32x4 a1 = *(const f32x4*)&As[row * 128 + (((s0 + 1) ^ (row & 15)) * 4)];
        unsigned int* ap = (unsigned int*)&af[m];
        ap[0] = pk2(a0.x, a0.y); ap[1] = pk2(a0.z, a0.w);
        ap[2] = pk2(a1.x, a1.y); ap[3] = pk2(a1.z, a1.w);
        if (wc == 0) {
          if (m == 0) { qv.x = quant4(a0); qv.y = quant4(a1); }
          else        { qv.z = quant4(a0); qv.w = quant4(a1); }
        }
      }
      if (wc == 0) {
        const int G = z * 64 + t * 4 + kk;    // absolute 32-col K-group
        *(uint4*)(adj8 + tbase + (size_t)(G * 2 + wr) * 1024 + (size_t)lane * 16) = qv;
      }
#pragma unroll
      for (int n = 0; n < 4; ++n) {
        const int d = wc * 64 + n * 16 + fr;
        bfr[n] = *(const bf16x8*)&Bs[d * 128 + (((kk * 4 + g) ^ (d & 15)) * 8)];
      }
#pragma unroll
      for (int m = 0; m < 2; ++m)
#pragma unroll
        for (int n = 0; n < 4; ++n)
          acc[m][n] = __builtin_amdgcn_mfma_f32_16x16x32_bf16(af[m], bfr[n], acc[m][n], 0, 0, 0);
    }
    __syncthreads();                          // protect LDS overwrite next step
  }

  unsigned short* gO = agg_p + (((size_t)z * R_ + r) * N_ + row0) * D_;
#pragma unroll
  for (int m = 0; m < 2; ++m)
#pragma unroll
    for (int n = 0; n < 4; ++n)
#pragma unroll
      for (int j = 0; j < 4; ++j) {
        int rl = wr * 32 + m * 16 + cr4 + j;
        int cl = wc * 64 + n * 16 + fr;
        gO[(size_t)rl * D_ + cl] = f2bf(acc[m][n][j]);
      }
}

// ---- Layer-2 GEMM: u8 tiled adj; wave partition mf1/nf8 (wave w = rows w*16..+16,
//      all 128 cols) so each dequanted A-frag feeds 8 MFMAs instead of 4. ----
__global__ __launch_bounds__(256, 4) void gcn_gemm2(
    const unsigned char* __restrict__ adj8,   // tiled u8 (from gemm1)
    const unsigned short* __restrict__ embT,  // [D][N] bf16, scaled 1/256
    unsigned short* __restrict__ agg_p)       // [KSPLIT][R][N][D] bf16
{
  __shared__ unsigned char  A8[64 * 64];      // 4 KB: linear copy of one step-tile
  __shared__ unsigned short Bs[D_ * 64];      // 16 KB: slot s stored at s^(d&7)

  const int tid  = threadIdx.x;
  const int lane = tid & 63;
  const int w    = tid >> 6;                  // wave w: rows w*16 .. w*16+16
  const int fr   = lane & 15;
  const int g    = lane >> 4;
  const int cr4  = g * 4;

  const int ntile = blockIdx.x;
  const int r     = blockIdx.y;
  const int z     = blockIdx.z;
  const int row0  = ntile * BM;
  const int k0    = z * (N_ / KSPLIT);
  const size_t tbase = (size_t)(r * 64 + ntile) * 262144;

  f32x4 acc[8];
#pragma unroll
  for (int n = 0; n < 8; ++n)
    acc[n] = (f32x4){0.f, 0.f, 0.f, 0.f};

  for (int t = 0; t < 32; ++t) {              // BK=64 steps
    const int S = z * 32 + t;
    // A: 1 instr/wave; wave w stages chunk w (1 KB), pure sequential memcpy
    gld16(adj8 + tbase + (size_t)S * 4096 + (size_t)w * 1024 + (size_t)lane * 16,
          A8 + w * 1024);
    // B: 4 instrs/wave, each 1 KB = 8 rows x 128 B (8 slots); source pre-swizzled
#pragma unroll
    for (int i = 0; i < 4; ++i) {
      const int rowbase = (w * 4 + i) * 8;
      const int rb   = rowbase + (lane >> 3);
      const int slot = (lane & 7) ^ (rb & 7);
      gld16(embT + (size_t)rb * N_ + k0 + t * 64 + slot * 8, Bs + rowbase * 64);
    }
    __syncthreads();

#pragma unroll
    for (int kk = 0; kk < 2; ++kk) {
      // A-frag: row = w*16+fr -> writer keying (wr=w>>1, m=w&1): 8B at
      // (kk*2 + (w>>1))*1024 + lane*16 + (w&1)*8
      unsigned long long v = *(const unsigned long long*)
          &A8[((kk * 2 + (w >> 1)) * 64 + lane) * 16 + (w & 1) * 8];
      bf16x8 af;
      unsigned int* ap = (unsigned int*)&af;
      ap[0] = pk2((float)((unsigned)(v      ) & 255), (float)((unsigned)(v >>  8) & 255));
      ap[1] = pk2((float)((unsigned)(v >> 16) & 255), (float)((unsigned)(v >> 24) & 255));
      ap[2] = pk2((float)((unsigned)(v >> 32) & 255), (float)((unsigned)(v >> 40) & 255));
      ap[3] = pk2((float)((unsigned)(v >> 48) & 255), (float)((unsigned)(v >> 56) & 255));
#pragma unroll
      for (int n = 0; n < 8; ++n) {
        const int d = n * 16 + fr;
        bf16x8 bfr = *(const bf16x8*)&Bs[d * 64 + (((kk * 4 + g) ^ (d & 7)) * 8)];
        acc[n] = __builtin_amdgcn_mfma_f32_16x16x32_bf16(af, bfr, acc[n], 0, 0, 0);
      }
    }
    __syncthreads();
  }

  unsigned short* gO = agg_p + (((size_t)z * R_ + r) * N_ + row0) * D_;
#pragma unroll
  for (int n = 0; n < 8; ++n)
#pragma unroll
    for (int j = 0; j < 4; ++j) {
      int rl = w * 16 + cr4 + j;
      int cl = n * 16 + fr;
      gO[(size_t)rl * D_ + cl] = f2bf(acc[n][j]);
    }
}

// Pass 2: tmp = agg_p @ rel^T summed over z,r; out = relu(mean_r); embT (scaled) for layer 2
__global__ __launch_bounds__(256) void gcn_pass2(
    const unsigned short* __restrict__ agg_p,  // [KSPLIT][R][N][D] bf16
    const unsigned short* __restrict__ relb,   // [R][D][D] bf16
    float* __restrict__ out,                   // [N][D] f32
    unsigned short* __restrict__ embT,         // [D][N] bf16
    int write_out, int write_embT)
{
  const int tid  = threadIdx.x;
  const int lane = tid & 63;
  const int w    = tid >> 6;
  const int n0   = blockIdx.x * 16;
  const int col0 = w * 32;
  const int fr   = lane & 15;
  const int e8   = (lane >> 4) * 8;
  const int cr4  = (lane >> 4) * 4;

  f32x4 tacc[2];
  tacc[0] = (f32x4){0.f, 0.f, 0.f, 0.f};
  tacc[1] = (f32x4){0.f, 0.f, 0.f, 0.f};

  for (int r = 0; r < R_; ++r) {
    bf16x8 a[2][4], b[2][4];
#pragma unroll
    for (int zz = 0; zz < 2; ++zz)
#pragma unroll
      for (int kk = 0; kk < 4; ++kk)
        a[zz][kk] = *(const bf16x8*)&agg_p[(((size_t)zz * R_ + r) * N_ + n0 + fr) * D_ + kk * 32 + e8];
#pragma unroll
    for (int n = 0; n < 2; ++n)
#pragma unroll
      for (int kk = 0; kk < 4; ++kk)
        b[n][kk] = *(const bf16x8*)&relb[(size_t)r * D_ * D_ + (col0 + n * 16 + fr) * D_ + kk * 32 + e8];
#pragma unroll
    for (int n = 0; n < 2; ++n)
#pragma unroll
      for (int kk = 0; kk < 4; ++kk)
#pragma unroll
        for (int zz = 0; zz < 2; ++zz)
          tacc[n] = __builtin_amdgcn_mfma_f32_16x16x32_bf16(a[zz][kk], b[n][kk], tacc[n], 0, 0, 0);
  }

#pragma unroll
  for (int n = 0; n < 2; ++n)
#pragma unroll
    for (int j = 0; j < 4; ++j) {
      int row = n0 + cr4 + j;
      int col = col0 + n * 16 + fr;
      float v = tacc[n][j] * 0.125f;
      v = v > 0.f ? v : 0.f;
      if (write_out)  out[(size_t)row * D_ + col] = v;
      if (write_embT) embT[(size_t)col * N_ + row] = f2bf(v * 0.00390625f);  // fold 1/256 for u8 layer-2
    }
}

extern "C" void kernel_launch(void* const* d_in, const int* in_sizes, int n_in,
                              void* d_out, int out_size, void* d_ws, size_t ws_size,
                              hipStream_t stream) {
  const float* adj = (const float*)d_in[0];   // [R][N][N]
  const float* emb = (const float*)d_in[1];   // [N][D]
  const float* rel = (const float*)d_in[2];   // [R][D][D]
  float* out = (float*)d_out;                 // [N][D] f32

  unsigned short* embT  = (unsigned short*)d_ws;                 // 1 MB
  unsigned short* relb  = embT + (size_t)N_ * D_;                // 256 KB
  unsigned short* agg_p = relb + (size_t)R_ * D_ * D_;           // 16 MB
  unsigned char*  adj8  = (unsigned char*)(agg_p + (size_t)2 * R_ * N_ * D_);  // 128 MB

  k_init_embT<<<(N_ * D_) / 256, 256, 0, stream>>>(emb, embT);
  k_init_rel<<<(R_ * D_ * D_) / 256, 256, 0, stream>>>(rel, relb);

  dim3 grid(N_ / BM, R_, KSPLIT);
  gcn_gemm1<<<grid, 256, 0, stream>>>(adj, embT, adj8, agg_p);
  gcn_pass2<<<N_ / 16, 256, 0, stream>>>(agg_p, relb, out, embT, /*write_out=*/0, /*write_embT=*/1);
  gcn_gemm2<<<grid, 256, 0, stream>>>(adj8, embT, agg_p);
  gcn_pass2<<<N_ / 16, 256, 0, stream>>>(agg_p, relb, out, embT, /*write_out=*/1, /*write_embT=*/0);
}